// Round 9
// baseline (294.764 us; speedup 1.0000x reference)
//
#include <hip/hip_runtime.h>

#define NN 100000
#define NE 1600000
#define NBK 196           // buckets of 512 nodes: b = dst >> 9
#define BNODES 512
#define BCAP 8960         // records per bucket; mean 8192, sd ~90 -> +8.5 sigma
#define OVF_CAP 65536
#define EMASK 0x1FFFFF    // e < 1.6M < 2^21

// Workspace layout (4-byte words):
//   [0, 10240)              Mcat [kb][j][w]: Mcat[kb*256+j*4+w] = M[kb*4+w][j]
//                           M (160x64) = [W2a ; W1a@W2b ; W1b@W2b]
//   [10240, 10304)          vb (64) = b1 @ W2b
//   [10496, +196)           gcur (int per bucket)
//   [10696]                 ovf_cnt
//   [10752, +3512320)       recs    (int2: src, (dst&511)<<21 | e), NBK*BCAP
//   [3523072, +3512320)     ordered (int2: src, e), NBK*BCAP
//   [7035392, +NN)          row_start
//   [7135392, +NN)          counts
//   [7235392, ...)          ovf (int4: dst, src, e, 0), OVF_CAP

__device__ __forceinline__ float mcat_val(const float* __restrict__ W1,
                                          const float* __restrict__ W2,
                                          int r, int j) {
    if (r < 64) return W2[r * 64 + j];                  // W2a
    float acc = 0.f;
    if (r < 128) {
        int i = r - 64;                                 // W1a @ W2b
        for (int h = 0; h < 128; ++h)
            acc = fmaf(W1[i * 128 + h], W2[(64 + h) * 64 + j], acc);
    } else {
        int i = r - 128;                                // W1b @ W2b
        for (int h = 0; h < 128; ++h)
            acc = fmaf(W1[(64 + i) * 128 + h], W2[(64 + h) * 64 + j], acc);
    }
    return acc;
}

__device__ __forceinline__ void spill_rec(int* ovf_cnt, int4* ovf, int b, int2 r) {
    int dst = b * BNODES + (int)((unsigned)r.y >> 21);
    int e = r.y & EMASK;
    int op = atomicAdd(ovf_cnt, 1);
    if (op < OVF_CAP) ovf[op] = make_int4(dst, r.x, e, 0);
}

// Blocks 0..255: stage edge records per dst-bucket in LDS rings; flush
// 8-record (64B) aligned groups with one global atomic each.
// Block 256: precompute Mcat/vb (fused to hide the serial small kernel).
__global__ __launch_bounds__(1024)
void bin_kernel(const int* __restrict__ ei,
                const float* __restrict__ W1, const float* __restrict__ b1,
                const float* __restrict__ W2,
                float* __restrict__ Mcat, float* __restrict__ vb,
                int* __restrict__ gcur,
                int* __restrict__ ovf_cnt,
                int2* __restrict__ recs,
                int4* __restrict__ ovf) {
    int tid = threadIdx.x;
    if (blockIdx.x == 256) {                            // fused precompute
        for (int idx = tid; idx < 160 * 64 + 64; idx += 1024) {
            if (idx < 160 * 64) {
                int kb = idx >> 8, j = (idx >> 2) & 63, w = idx & 3;
                Mcat[idx] = mcat_val(W1, W2, kb * 4 + w, j);
            } else {
                int j = idx - 160 * 64;
                float acc = 0.f;
                for (int h = 0; h < 128; ++h)
                    acc = fmaf(b1[h], W2[(64 + h) * 64 + j], acc);
                vb[j] = acc;
            }
        }
        return;
    }

    __shared__ int2 ring[NBK][32];
    __shared__ int cur[NBK], flushed[NBK];
    if (tid < NBK) { cur[tid] = 0; flushed[tid] = 0; }
    __syncthreads();

    const int per = NE / 256;                           // 6250, exact
    int base = blockIdx.x * per;
    for (int it = 0; it < 7; ++it) {
        int idx = it * 1024 + tid;
        if (idx < per) {
            int e = base + idx;
            int src = ei[e], dst = ei[NE + e];
            int b = dst >> 9;
            int p = atomicAdd(&cur[b], 1);
            ring[b][p & 31] = make_int2(src, ((dst & 511) << 21) | e);
        }
        __syncthreads();
        if (tid < NBK) {
            int f = flushed[tid];
            int g8 = ((cur[tid] - f) >> 3) << 3;
            if (g8 > 0) {
                int gb = atomicAdd(&gcur[tid], g8);
                int2* rb = recs + (size_t)tid * BCAP;
                for (int k = 0; k < g8; k += 2) {
                    int2 r0 = ring[tid][(f + k) & 31];
                    int2 r1 = ring[tid][(f + k + 1) & 31];
                    if (gb + k + 1 < BCAP) {            // gb,k even -> 16B aligned
                        *reinterpret_cast<int4*>(&rb[gb + k]) =
                            make_int4(r0.x, r0.y, r1.x, r1.y);
                    } else {
                        spill_rec(ovf_cnt, ovf, tid, r0);
                        spill_rec(ovf_cnt, ovf, tid, r1);
                    }
                }
                flushed[tid] = f + g8;
            }
        }
        __syncthreads();
    }
    // final partial flush (<8 records per bucket)
    if (tid < NBK) {
        int f = flushed[tid];
        int rem = cur[tid] - f;
        if (rem > 0) {
            int gb = atomicAdd(&gcur[tid], rem);
            int2* rb = recs + (size_t)tid * BCAP;
            for (int k = 0; k < rem; ++k) {
                int2 r = ring[tid][(f + k) & 31];
                if (gb + k < BCAP) rb[gb + k] = r;
                else spill_rec(ovf_cnt, ovf, tid, r);
            }
        }
    }
}

// One block per bucket: LDS histogram -> LDS scan -> scatter into per-node
// contiguous lists. All scattered writes confined to this block's 70KB region.
__global__ __launch_bounds__(1024)
void sort_kernel(const int* __restrict__ gcur,
                 const int2* __restrict__ recs,
                 int2* __restrict__ ordered,
                 int* __restrict__ row_start,
                 int* __restrict__ counts) {
    __shared__ int cnt[BNODES], s[BNODES], cur[BNODES];
    int b = blockIdx.x, tid = threadIdx.x;
    int nrec = gcur[b]; if (nrec > BCAP) nrec = BCAP;
    const int2* rb = recs + (size_t)b * BCAP;
    int2* ob = ordered + (size_t)b * BCAP;

    if (tid < BNODES) cnt[tid] = 0;
    __syncthreads();
    for (int i = tid; i < nrec; i += 1024)
        atomicAdd(&cnt[(unsigned)rb[i].y >> 21], 1);
    __syncthreads();
    if (tid < BNODES) s[tid] = cnt[tid];
    __syncthreads();
    for (int off = 1; off < BNODES; off <<= 1) {        // inclusive scan
        int t = 0;
        if (tid < BNODES && tid >= off) t = s[tid - off];
        __syncthreads();
        if (tid < BNODES) s[tid] += t;
        __syncthreads();
    }
    int obase = b * BCAP;
    if (tid < BNODES) {
        int excl = s[tid] - cnt[tid];
        cur[tid] = excl;
        int n = b * BNODES + tid;
        if (n < NN) { row_start[n] = obase + excl; counts[n] = cnt[tid]; }
    }
    __syncthreads();
    for (int i = tid; i < nrec; i += 1024) {
        int2 r = rb[i];
        int dl = (unsigned)r.y >> 21;
        int pos = atomicAdd(&cur[dl], 1);
        ob[pos] = make_int2(r.x, r.y & EMASK);
    }
}

// One wave per node: stage pair chunk to LDS (coalesced), broadcast-read it,
// 8-deep unrolled x/ea accumulate, then float4 GEMV. (NO non-temporal loads.)
__global__ __launch_bounds__(1024, 2)
void gather_kernel(const float* __restrict__ x,
                   const float* __restrict__ ea,
                   const float* __restrict__ b2,
                   const float* __restrict__ Mcat,
                   const float* __restrict__ vb,
                   const int* __restrict__ row_start,
                   const int* __restrict__ counts,
                   const int2* __restrict__ pairs,
                   float* __restrict__ out) {
    __shared__ __align__(16) float m4[40 * 256];        // 40 KB [kb][j][w]
    __shared__ __align__(16) float v_lds[16][160];
    __shared__ __align__(8)  int2  p_lds[16][64];
    __shared__ float vb_lds[64], b2_lds[64];

    for (int i = threadIdx.x; i < 10240; i += 1024) m4[i] = Mcat[i];
    if (threadIdx.x < 64) {
        vb_lds[threadIdx.x] = vb[threadIdx.x];
        b2_lds[threadIdx.x] = b2[threadIdx.x];
    }
    __syncthreads();

    int wave = threadIdx.x >> 6;
    int lane = threadIdx.x & 63;
    int elane = lane & 31;
    int nwt = gridDim.x * 16;

    for (int n = blockIdx.x * 16 + wave; n < NN; n += nwt) {
        int dcnt = counts[n];
        int c = row_start[n];
        float xa0 = 0.f, xa1 = 0.f, xa2 = 0.f, xa3 = 0.f;
        float xa4 = 0.f, xa5 = 0.f, xa6 = 0.f, xa7 = 0.f;
        float e0a = 0.f, e1a = 0.f, e2a = 0.f, e3a = 0.f;
        int rem = dcnt;
        while (rem > 0) {
            int m = rem < 64 ? rem : 64;
            if (lane < m) p_lds[wave][lane] = pairs[c + lane];
            __threadfence_block();
            const int2* pr = p_lds[wave];
            int i = 0;
            for (; i + 8 <= m; i += 8) {
                int2 q0 = pr[i],     q1 = pr[i + 1], q2 = pr[i + 2], q3 = pr[i + 3];
                int2 q4 = pr[i + 4], q5 = pr[i + 5], q6 = pr[i + 6], q7 = pr[i + 7];
                xa0 += x[(size_t)q0.x * 64 + lane];
                xa1 += x[(size_t)q1.x * 64 + lane];
                xa2 += x[(size_t)q2.x * 64 + lane];
                xa3 += x[(size_t)q3.x * 64 + lane];
                xa4 += x[(size_t)q4.x * 64 + lane];
                xa5 += x[(size_t)q5.x * 64 + lane];
                xa6 += x[(size_t)q6.x * 64 + lane];
                xa7 += x[(size_t)q7.x * 64 + lane];
                int eA = (lane < 32) ? q0.y : q1.y;
                int eB = (lane < 32) ? q2.y : q3.y;
                int eC = (lane < 32) ? q4.y : q5.y;
                int eD = (lane < 32) ? q6.y : q7.y;
                e0a += ea[(size_t)eA * 32 + elane];
                e1a += ea[(size_t)eB * 32 + elane];
                e2a += ea[(size_t)eC * 32 + elane];
                e3a += ea[(size_t)eD * 32 + elane];
            }
            for (; i + 4 <= m; i += 4) {
                int2 q0 = pr[i], q1 = pr[i + 1], q2 = pr[i + 2], q3 = pr[i + 3];
                xa0 += x[(size_t)q0.x * 64 + lane];
                xa1 += x[(size_t)q1.x * 64 + lane];
                xa2 += x[(size_t)q2.x * 64 + lane];
                xa3 += x[(size_t)q3.x * 64 + lane];
                int eA = (lane < 32) ? q0.y : q1.y;
                int eB = (lane < 32) ? q2.y : q3.y;
                e0a += ea[(size_t)eA * 32 + elane];
                e1a += ea[(size_t)eB * 32 + elane];
            }
            for (; i + 2 <= m; i += 2) {
                int2 q0 = pr[i], q1 = pr[i + 1];
                xa0 += x[(size_t)q0.x * 64 + lane];
                xa1 += x[(size_t)q1.x * 64 + lane];
                int eA = (lane < 32) ? q0.y : q1.y;
                e0a += ea[(size_t)eA * 32 + elane];
            }
            if (i < m) {
                int2 q0 = pr[i];
                xa0 += x[(size_t)q0.x * 64 + lane];
                if (lane < 32) e0a += ea[(size_t)q0.y * 32 + elane];
            }
            rem -= m;
            c += m;
        }
        float xacc = ((xa0 + xa1) + (xa2 + xa3)) + ((xa4 + xa5) + (xa6 + xa7));
        float eacc = (e0a + e1a) + (e2a + e3a);
        eacc += __shfl_xor(eacc, 32);

        v_lds[wave][lane] = x[(size_t)n * 64 + lane];   // self features
        v_lds[wave][64 + lane] = xacc;                  // Sx
        if (lane < 32) v_lds[wave][128 + elane] = eacc; // Sea
        __threadfence_block();

        float acc = b2_lds[lane] + (float)dcnt * vb_lds[lane];
        #pragma unroll
        for (int kb = 0; kb < 40; ++kb) {
            float4 vv = *reinterpret_cast<const float4*>(&v_lds[wave][kb * 4]);
            float4 mm = *reinterpret_cast<const float4*>(&m4[kb * 256 + lane * 4]);
            acc = fmaf(vv.x, mm.x, acc);
            acc = fmaf(vv.y, mm.y, acc);
            acc = fmaf(vv.z, mm.z, acc);
            acc = fmaf(vv.w, mm.w, acc);
        }
        out[(size_t)n * 64 + lane] = acc;
    }
}

// Spilled edges (expected: none): out[dst] += vb + Mx^T x[src] + Mea^T ea[e].
__global__ void ovf_kernel(const float* __restrict__ x,
                           const float* __restrict__ ea,
                           const float* __restrict__ Mcat,
                           const float* __restrict__ vb,
                           const int* __restrict__ ovf_cnt,
                           const int4* __restrict__ ovf,
                           float* __restrict__ out) {
    int no = *ovf_cnt;
    if (no > OVF_CAP) no = OVF_CAP;
    int wv = (blockIdx.x * blockDim.x + threadIdx.x) >> 6;
    int lane = threadIdx.x & 63;
    int nw = (gridDim.x * blockDim.x) >> 6;
    for (int o = wv; o < no; o += nw) {
        int4 t = ovf[o];   // (dst, src, e, _)
        float acc = vb[lane];
        #pragma unroll
        for (int kb = 16; kb < 32; ++kb) {              // Mx rows 64..127
            float4 xv = *reinterpret_cast<const float4*>(&x[(size_t)t.y * 64 + (kb - 16) * 4]);
            float4 mm = *reinterpret_cast<const float4*>(&Mcat[kb * 256 + lane * 4]);
            acc = fmaf(xv.x, mm.x, acc);
            acc = fmaf(xv.y, mm.y, acc);
            acc = fmaf(xv.z, mm.z, acc);
            acc = fmaf(xv.w, mm.w, acc);
        }
        #pragma unroll
        for (int kb = 32; kb < 40; ++kb) {              // Mea rows 128..159
            float4 av = *reinterpret_cast<const float4*>(&ea[(size_t)t.z * 32 + (kb - 32) * 4]);
            float4 mm = *reinterpret_cast<const float4*>(&Mcat[kb * 256 + lane * 4]);
            acc = fmaf(av.x, mm.x, acc);
            acc = fmaf(av.y, mm.y, acc);
            acc = fmaf(av.z, mm.z, acc);
            acc = fmaf(av.w, mm.w, acc);
        }
        atomicAdd(&out[(size_t)t.x * 64 + lane], acc);
    }
}

extern "C" void kernel_launch(void* const* d_in, const int* in_sizes, int n_in,
                              void* d_out, int out_size, void* d_ws, size_t ws_size,
                              hipStream_t stream) {
    const float* x  = (const float*)d_in[0];
    const int*   ei = (const int*)d_in[1];
    const float* ea = (const float*)d_in[2];
    const float* W1 = (const float*)d_in[5];
    const float* b1 = (const float*)d_in[6];
    const float* W2 = (const float*)d_in[7];
    const float* b2 = (const float*)d_in[8];

    float* ws        = (float*)d_ws;
    float* Mcat      = ws;
    float* vb        = ws + 10240;
    int*   gcur      = (int*)(ws + 10496);
    int*   ovf_cnt   = gcur + 200;
    int2*  recs      = (int2*)(ws + 10752);
    int2*  ordered   = recs + (size_t)NBK * BCAP;
    int*   row_start = (int*)(ordered + (size_t)NBK * BCAP);
    int*   counts    = row_start + NN;
    int4*  ovf       = (int4*)(counts + NN);

    (void)hipMemsetAsync(gcur, 0, 256 * sizeof(int), stream);  // gcur + ovf_cnt

    bin_kernel<<<257, 1024, 0, stream>>>(ei, W1, b1, W2, Mcat, vb,
                                         gcur, ovf_cnt, recs, ovf);
    sort_kernel<<<NBK, 1024, 0, stream>>>(gcur, recs, ordered, row_start, counts);
    gather_kernel<<<512, 1024, 0, stream>>>(x, ea, b2, Mcat, vb, row_start,
                                            counts, ordered, (float*)d_out);
    ovf_kernel<<<16, 256, 0, stream>>>(x, ea, Mcat, vb, ovf_cnt, ovf, (float*)d_out);
}

// Round 10
// 180.336 us; speedup vs baseline: 1.6345x; 1.6345x over previous
//
#include <hip/hip_runtime.h>

#define NN 100000
#define NE 1600000
#define NBK 196           // buckets of 512 nodes: b = dst >> 9
#define BNODES 512
#define BCAP 8960         // records per bucket; mean 8192, sd ~90 -> +8.5 sigma
#define OVF_CAP 65536
#define EMASK 0x1FFFFF    // e < 1.6M < 2^21

// Workspace layout (4-byte words):
//   [0, 10240)              Mcat [kb][j][w]: Mcat[kb*256+j*4+w] = M[kb*4+w][j]
//                           M (160x64) = [W2a ; W1a@W2b ; W1b@W2b]
//   [10240, 10304)          vb (64) = b1 @ W2b
//   [10496, +196)           gcur (int per bucket)
//   [10696]                 ovf_cnt
//   [10752, +3512320)       recs    (int2: src, (dst&511)<<21 | e), NBK*BCAP
//   [3523072, +3512320)     ordered (int2: src, e), NBK*BCAP
//   [7035392, +NN)          row_start
//   [7135392, +NN)          counts
//   [7235392, ...)          ovf (int4: dst, src, e, 0), OVF_CAP

__device__ __forceinline__ float mcat_val(const float* __restrict__ W1,
                                          const float* __restrict__ W2,
                                          int r, int j) {
    if (r < 64) return W2[r * 64 + j];                  // W2a
    float acc = 0.f;
    if (r < 128) {
        int i = r - 64;                                 // W1a @ W2b
        for (int h = 0; h < 128; ++h)
            acc = fmaf(W1[i * 128 + h], W2[(64 + h) * 64 + j], acc);
    } else {
        int i = r - 128;                                // W1b @ W2b
        for (int h = 0; h < 128; ++h)
            acc = fmaf(W1[(64 + i) * 128 + h], W2[(64 + h) * 64 + j], acc);
    }
    return acc;
}

__global__ void precompute_kernel(const float* __restrict__ W1,
                                  const float* __restrict__ b1,
                                  const float* __restrict__ W2,
                                  float* __restrict__ Mcat,
                                  float* __restrict__ vb) {
    int idx = blockIdx.x * blockDim.x + threadIdx.x;
    if (idx < 160 * 64) {
        int kb = idx >> 8, j = (idx >> 2) & 63, w = idx & 3;
        Mcat[idx] = mcat_val(W1, W2, kb * 4 + w, j);
    } else if (idx < 160 * 64 + 64) {
        int j = idx - 160 * 64;
        float acc = 0.f;
        for (int h = 0; h < 128; ++h)
            acc = fmaf(b1[h], W2[(64 + h) * 64 + j], acc);
        vb[j] = acc;
    }
}

__device__ __forceinline__ void spill_rec(int* ovf_cnt, int4* ovf, int b, int2 r) {
    int dst = b * BNODES + (int)((unsigned)r.y >> 21);
    int e = r.y & EMASK;
    int op = atomicAdd(ovf_cnt, 1);
    if (op < OVF_CAP) ovf[op] = make_int4(dst, r.x, e, 0);
}

// Stage edge records per dst-bucket in LDS rings; flush 8-record (64B) aligned
// groups with one global atomic each.
__global__ __launch_bounds__(1024)
void bin_kernel(const int* __restrict__ ei,
                int* __restrict__ gcur,
                int* __restrict__ ovf_cnt,
                int2* __restrict__ recs,
                int4* __restrict__ ovf) {
    __shared__ int2 ring[NBK][32];
    __shared__ int cur[NBK], flushed[NBK];
    int tid = threadIdx.x;
    if (tid < NBK) { cur[tid] = 0; flushed[tid] = 0; }
    __syncthreads();

    const int per = NE / 256;                           // 6250, exact
    int base = blockIdx.x * per;
    for (int it = 0; it < 7; ++it) {
        int idx = it * 1024 + tid;
        if (idx < per) {
            int e = base + idx;
            int src = ei[e], dst = ei[NE + e];
            int b = dst >> 9;
            int p = atomicAdd(&cur[b], 1);
            ring[b][p & 31] = make_int2(src, ((dst & 511) << 21) | e);
        }
        __syncthreads();
        if (tid < NBK) {
            int f = flushed[tid];
            int g8 = ((cur[tid] - f) >> 3) << 3;
            if (g8 > 0) {
                int gb = atomicAdd(&gcur[tid], g8);
                int2* rb = recs + (size_t)tid * BCAP;
                for (int k = 0; k < g8; k += 2) {
                    int2 r0 = ring[tid][(f + k) & 31];
                    int2 r1 = ring[tid][(f + k + 1) & 31];
                    if (gb + k + 1 < BCAP) {            // gb,k even -> 16B aligned
                        *reinterpret_cast<int4*>(&rb[gb + k]) =
                            make_int4(r0.x, r0.y, r1.x, r1.y);
                    } else {
                        spill_rec(ovf_cnt, ovf, tid, r0);
                        spill_rec(ovf_cnt, ovf, tid, r1);
                    }
                }
                flushed[tid] = f + g8;
            }
        }
        __syncthreads();
    }
    // final partial flush (<8 records per bucket)
    if (tid < NBK) {
        int f = flushed[tid];
        int rem = cur[tid] - f;
        if (rem > 0) {
            int gb = atomicAdd(&gcur[tid], rem);
            int2* rb = recs + (size_t)tid * BCAP;
            for (int k = 0; k < rem; ++k) {
                int2 r = ring[tid][(f + k) & 31];
                if (gb + k < BCAP) rb[gb + k] = r;
                else spill_rec(ovf_cnt, ovf, tid, r);
            }
        }
    }
}

// One block per bucket: LDS histogram -> LDS scan -> scatter into per-node
// contiguous lists. All scattered writes confined to this block's 70KB region.
__global__ __launch_bounds__(1024)
void sort_kernel(const int* __restrict__ gcur,
                 const int2* __restrict__ recs,
                 int2* __restrict__ ordered,
                 int* __restrict__ row_start,
                 int* __restrict__ counts) {
    __shared__ int cnt[BNODES], s[BNODES], cur[BNODES];
    int b = blockIdx.x, tid = threadIdx.x;
    int nrec = gcur[b]; if (nrec > BCAP) nrec = BCAP;
    const int2* rb = recs + (size_t)b * BCAP;
    int2* ob = ordered + (size_t)b * BCAP;

    if (tid < BNODES) cnt[tid] = 0;
    __syncthreads();
    for (int i = tid; i < nrec; i += 1024)
        atomicAdd(&cnt[(unsigned)rb[i].y >> 21], 1);
    __syncthreads();
    if (tid < BNODES) s[tid] = cnt[tid];
    __syncthreads();
    for (int off = 1; off < BNODES; off <<= 1) {        // inclusive scan
        int t = 0;
        if (tid < BNODES && tid >= off) t = s[tid - off];
        __syncthreads();
        if (tid < BNODES) s[tid] += t;
        __syncthreads();
    }
    int obase = b * BCAP;
    if (tid < BNODES) {
        int excl = s[tid] - cnt[tid];
        cur[tid] = excl;
        int n = b * BNODES + tid;
        if (n < NN) { row_start[n] = obase + excl; counts[n] = cnt[tid]; }
    }
    __syncthreads();
    for (int i = tid; i < nrec; i += 1024) {
        int2 r = rb[i];
        int dl = (unsigned)r.y >> 21;
        int pos = atomicAdd(&cur[dl], 1);
        ob[pos] = make_int2(r.x, r.y & EMASK);
    }
}

// One wave per node: stage pair chunk to LDS (coalesced), broadcast-read it,
// 4-deep unrolled x/ea accumulate, then float4 GEMV from LDS-cached Mcat.
__global__ __launch_bounds__(1024, 2)
void gather_kernel(const float* __restrict__ x,
                   const float* __restrict__ ea,
                   const float* __restrict__ b2,
                   const float* __restrict__ Mcat,
                   const float* __restrict__ vb,
                   const int* __restrict__ row_start,
                   const int* __restrict__ counts,
                   const int2* __restrict__ pairs,
                   float* __restrict__ out) {
    __shared__ __align__(16) float m4[40 * 256];        // 40 KB [kb][j][w]
    __shared__ __align__(16) float v_lds[16][160];
    __shared__ __align__(8)  int2  p_lds[16][64];
    __shared__ float vb_lds[64], b2_lds[64];

    for (int i = threadIdx.x; i < 10240; i += 1024) m4[i] = Mcat[i];
    if (threadIdx.x < 64) {
        vb_lds[threadIdx.x] = vb[threadIdx.x];
        b2_lds[threadIdx.x] = b2[threadIdx.x];
    }
    __syncthreads();

    int wave = threadIdx.x >> 6;
    int lane = threadIdx.x & 63;
    int elane = lane & 31;
    int nwt = gridDim.x * 16;

    for (int n = blockIdx.x * 16 + wave; n < NN; n += nwt) {
        int dcnt = counts[n];
        int c = row_start[n];
        float xa0 = 0.f, xa1 = 0.f, xa2 = 0.f, xa3 = 0.f;
        float e0a = 0.f, e1a = 0.f;
        int rem = dcnt;
        while (rem > 0) {
            int m = rem < 64 ? rem : 64;
            if (lane < m) p_lds[wave][lane] = pairs[c + lane];
            __threadfence_block();
            const int2* pr = p_lds[wave];
            int i = 0;
            for (; i + 4 <= m; i += 4) {
                int2 q0 = pr[i], q1 = pr[i + 1], q2 = pr[i + 2], q3 = pr[i + 3];
                xa0 += x[(size_t)q0.x * 64 + lane];
                xa1 += x[(size_t)q1.x * 64 + lane];
                xa2 += x[(size_t)q2.x * 64 + lane];
                xa3 += x[(size_t)q3.x * 64 + lane];
                int eA = (lane < 32) ? q0.y : q1.y;
                int eB = (lane < 32) ? q2.y : q3.y;
                e0a += ea[(size_t)eA * 32 + elane];
                e1a += ea[(size_t)eB * 32 + elane];
            }
            for (; i + 2 <= m; i += 2) {
                int2 q0 = pr[i], q1 = pr[i + 1];
                xa0 += x[(size_t)q0.x * 64 + lane];
                xa1 += x[(size_t)q1.x * 64 + lane];
                int eA = (lane < 32) ? q0.y : q1.y;
                e0a += ea[(size_t)eA * 32 + elane];
            }
            if (i < m) {
                int2 q0 = pr[i];
                xa0 += x[(size_t)q0.x * 64 + lane];
                if (lane < 32) e0a += ea[(size_t)q0.y * 32 + elane];
            }
            rem -= m;
            c += m;
        }
        float xacc = (xa0 + xa1) + (xa2 + xa3);
        float eacc = e0a + e1a;
        eacc += __shfl_xor(eacc, 32);

        v_lds[wave][lane] = x[(size_t)n * 64 + lane];   // self features
        v_lds[wave][64 + lane] = xacc;                  // Sx
        if (lane < 32) v_lds[wave][128 + elane] = eacc; // Sea
        __threadfence_block();

        float acc = b2_lds[lane] + (float)dcnt * vb_lds[lane];
        #pragma unroll
        for (int kb = 0; kb < 40; ++kb) {
            float4 vv = *reinterpret_cast<const float4*>(&v_lds[wave][kb * 4]);
            float4 mm = *reinterpret_cast<const float4*>(&m4[kb * 256 + lane * 4]);
            acc = fmaf(vv.x, mm.x, acc);
            acc = fmaf(vv.y, mm.y, acc);
            acc = fmaf(vv.z, mm.z, acc);
            acc = fmaf(vv.w, mm.w, acc);
        }
        out[(size_t)n * 64 + lane] = acc;
    }
}

// Spilled edges (expected: none): out[dst] += vb + Mx^T x[src] + Mea^T ea[e].
__global__ void ovf_kernel(const float* __restrict__ x,
                           const float* __restrict__ ea,
                           const float* __restrict__ Mcat,
                           const float* __restrict__ vb,
                           const int* __restrict__ ovf_cnt,
                           const int4* __restrict__ ovf,
                           float* __restrict__ out) {
    int no = *ovf_cnt;
    if (no > OVF_CAP) no = OVF_CAP;
    int wv = (blockIdx.x * blockDim.x + threadIdx.x) >> 6;
    int lane = threadIdx.x & 63;
    int nw = (gridDim.x * blockDim.x) >> 6;
    for (int o = wv; o < no; o += nw) {
        int4 t = ovf[o];   // (dst, src, e, _)
        float acc = vb[lane];
        #pragma unroll
        for (int kb = 16; kb < 32; ++kb) {              // Mx rows 64..127
            float4 xv = *reinterpret_cast<const float4*>(&x[(size_t)t.y * 64 + (kb - 16) * 4]);
            float4 mm = *reinterpret_cast<const float4*>(&Mcat[kb * 256 + lane * 4]);
            acc = fmaf(xv.x, mm.x, acc);
            acc = fmaf(xv.y, mm.y, acc);
            acc = fmaf(xv.z, mm.z, acc);
            acc = fmaf(xv.w, mm.w, acc);
        }
        #pragma unroll
        for (int kb = 32; kb < 40; ++kb) {              // Mea rows 128..159
            float4 av = *reinterpret_cast<const float4*>(&ea[(size_t)t.z * 32 + (kb - 32) * 4]);
            float4 mm = *reinterpret_cast<const float4*>(&Mcat[kb * 256 + lane * 4]);
            acc = fmaf(av.x, mm.x, acc);
            acc = fmaf(av.y, mm.y, acc);
            acc = fmaf(av.z, mm.z, acc);
            acc = fmaf(av.w, mm.w, acc);
        }
        atomicAdd(&out[(size_t)t.x * 64 + lane], acc);
    }
}

extern "C" void kernel_launch(void* const* d_in, const int* in_sizes, int n_in,
                              void* d_out, int out_size, void* d_ws, size_t ws_size,
                              hipStream_t stream) {
    const float* x  = (const float*)d_in[0];
    const int*   ei = (const int*)d_in[1];
    const float* ea = (const float*)d_in[2];
    const float* W1 = (const float*)d_in[5];
    const float* b1 = (const float*)d_in[6];
    const float* W2 = (const float*)d_in[7];
    const float* b2 = (const float*)d_in[8];

    float* ws        = (float*)d_ws;
    float* Mcat      = ws;
    float* vb        = ws + 10240;
    int*   gcur      = (int*)(ws + 10496);
    int*   ovf_cnt   = gcur + 200;
    int2*  recs      = (int2*)(ws + 10752);
    int2*  ordered   = recs + (size_t)NBK * BCAP;
    int*   row_start = (int*)(ordered + (size_t)NBK * BCAP);
    int*   counts    = row_start + NN;
    int4*  ovf       = (int4*)(counts + NN);

    (void)hipMemsetAsync(gcur, 0, 256 * sizeof(int), stream);  // gcur + ovf_cnt

    precompute_kernel<<<41, 256, 0, stream>>>(W1, b1, W2, Mcat, vb);
    bin_kernel<<<256, 1024, 0, stream>>>(ei, gcur, ovf_cnt, recs, ovf);
    sort_kernel<<<NBK, 1024, 0, stream>>>(gcur, recs, ordered, row_start, counts);
    gather_kernel<<<512, 1024, 0, stream>>>(x, ea, b2, Mcat, vb, row_start,
                                            counts, ordered, (float*)d_out);
    ovf_kernel<<<16, 256, 0, stream>>>(x, ea, Mcat, vb, ovf_cnt, ovf, (float*)d_out);
}